// Round 17
// baseline (188.466 us; speedup 1.0000x reference)
//
#include <hip/hip_runtime.h>
#include <hip/hip_bf16.h>
#include <stdint.h>

typedef __attribute__((ext_vector_type(4))) float floatx4;
typedef __attribute__((ext_vector_type(16))) float floatx16;
typedef __attribute__((ext_vector_type(4))) int intx4;
typedef __attribute__((ext_vector_type(8))) int intx8;
typedef __attribute__((ext_vector_type(2))) unsigned int uint2v;
typedef unsigned long long u64;

static constexpr int NROWS = 32768;
static constexpr int NCODE = 8192;
static constexpr int QELEMS = 8388608;
static constexpr float CSCALE = 8192.0f;

// Fragment-major fp8 layout: [row-tile32][k-slot16][row32][16B]
// -> every MFMA operand load is a coalesced 512B/half wave load from L2.

// ---- fused prep: [0,1024) z->z8f, [1024,3072) cb->c8f+norms, [3072,3088) amin ----
__global__ __launch_bounds__(256) void prep_all(
    const float* __restrict__ z, const float* __restrict__ cb,
    unsigned char* __restrict__ z8f, unsigned char* __restrict__ c8f,
    float* __restrict__ norms, u64* __restrict__ amin)
{
  const int bid = blockIdx.x;
  const int t = threadIdx.x;
  if (bid < 1024) {
    __shared__ float tile[32][260];
    const int b = bid & 31, db = (bid >> 5) & 7, hwb = bid >> 8;
    const int d0 = db * 32, hw0 = hwb * 256;
    const float* src = z + (((size_t)b * 256 + d0) << 10) + hw0;
#pragma unroll
    for (int i = 0; i < 8; ++i) {
      int idx = i * 256 + t;
      int r = idx >> 6, c4 = (idx & 63) * 4;
      *(floatx4*)&tile[r][c4] = *(const floatx4*)&src[((size_t)r << 10) + c4];
    }
    __syncthreads();
    const int dq = t & 3;
    const int hb = t >> 2;
#pragma unroll
    for (int it = 0; it < 4; ++it) {
      int h = hb + it * 64;
      float f[8];
#pragma unroll
      for (int i = 0; i < 8; ++i) f[i] = tile[dq * 8 + i][h];
      int lo = __builtin_amdgcn_cvt_pk_fp8_f32(f[0], f[1], 0, false);
      lo = __builtin_amdgcn_cvt_pk_fp8_f32(f[2], f[3], lo, true);
      int hi = __builtin_amdgcn_cvt_pk_fp8_f32(f[4], f[5], 0, false);
      hi = __builtin_amdgcn_cvt_pk_fp8_f32(f[6], f[7], hi, true);
      uint2v o; o[0] = (unsigned)lo; o[1] = (unsigned)hi;
      // row n = b*1024 + hw0 + h; dims d0+dq*8 .. +8
      int t32 = b * 32 + hwb * 8 + (h >> 5);
      int slot = db * 2 + (dq >> 1);
      size_t addr = (size_t)t32 * 8192 + slot * 512 + (h & 31) * 16 + (dq & 1) * 8;
      *(uint2v*)&z8f[addr] = o;
    }
  } else if (bid < 3072) {
    const int k = (bid - 1024) * 4 + (t >> 6);
    const int lane = t & 63;
    floatx4 v = *(const floatx4*)&cb[((size_t)k << 8) + lane * 4];
    float a = v[0] * CSCALE, b2 = v[1] * CSCALE, c = v[2] * CSCALE, d2 = v[3] * CSCALE;
    int r = __builtin_amdgcn_cvt_pk_fp8_f32(a, b2, 0, false);
    r = __builtin_amdgcn_cvt_pk_fp8_f32(c, d2, r, true);
    size_t addr = (size_t)(k >> 5) * 8192 + (lane >> 2) * 512 + (k & 31) * 16 + (lane & 3) * 4;
    *(unsigned int*)&c8f[addr] = (unsigned)r;
    float s = a * a + b2 * b2 + c * c + d2 * d2;  // ||8192 c||^2
#pragma unroll
    for (int off = 32; off; off >>= 1) s += __shfl_down(s, off);
    if (lane == 0) norms[k] = s;
  } else {
    const int base = (bid - 3072) * 2048;
#pragma unroll
    for (int i = 0; i < 8; ++i) amin[base + i * 256 + t] = ~0ull;
  }
}

// ---- main: MX-fp8 32x32x64; NO LDS, NO BARRIERS. A whole-K in VGPR; B read
// directly from L2 in fragment-major layout (coalesced 1KB wave loads).
// 4 cy-tiles/block; per-lane argmin + shfl32 + atomicMin (order-independent).
__global__ __launch_bounds__(256, 2) void gemm_argmin(
    const unsigned char* __restrict__ z8f, const unsigned char* __restrict__ c8f,
    const float* __restrict__ norms, u64* __restrict__ amin)
{
  const int tid = threadIdx.x;
  const int lane = tid & 63;
  const int wid = tid >> 6;
  const int wm = wid >> 1;  // code half (64 codes)
  const int wn = wid & 1;   // zrow half (128 zrows)

  // XCD chunked swizzle: nwg = 2048 (%8==0)
  const int bid = blockIdx.x;
  const int swz = (bid & 7) * 256 + (bid >> 3);
  const int cx = swz & 63;   // 64 code panels
  const int cyg = swz >> 6;  // 32 zrow groups (4 tiles of 256 rows)
  const int m0 = cx * 128;

  const int l31 = lane & 31;
  const int hi = lane >> 5;
  const int k2 = hi << 1;

  // ---- A (codes): coalesced fragment loads, whole K=256, once per block ----
  intx8 af[2][4];  // [ti][kt]
#pragma unroll
  for (int ti = 0; ti < 2; ++ti) {
    const unsigned char* ab = c8f + (size_t)((m0 >> 5) + wm * 2 + ti) * 8192
                              + (size_t)k2 * 512 + l31 * 16;
#pragma unroll
    for (int kt = 0; kt < 4; ++kt) {
      intx4 lo = *(const intx4*)(ab + kt * 2048);
      intx4 hv = *(const intx4*)(ab + kt * 2048 + 512);
      intx8 o;
#pragma unroll
      for (int w = 0; w < 4; ++w) { o[w] = lo[w]; o[4 + w] = hv[w]; }
      af[ti][kt] = o;
    }
  }

  // ---- norms: once per block ----
  floatx4 nv[2][4];
#pragma unroll
  for (int ti = 0; ti < 2; ++ti)
#pragma unroll
    for (int rq = 0; rq < 4; ++rq)
      nv[ti][rq] = *(const floatx4*)&norms[m0 + wm * 64 + ti * 32 + rq * 8 + 4 * hi];

  const unsigned char* bb = z8f + (size_t)(cyg * 32 + wn * 4) * 8192
                            + (size_t)k2 * 512 + (size_t)l31 * 16;

#pragma unroll 1
  for (int t = 0; t < 4; ++t) {
    floatx16 acc[2][4];
#pragma unroll
    for (int i = 0; i < 2; ++i)
#pragma unroll
      for (int j = 0; j < 4; ++j)
#pragma unroll
        for (int e = 0; e < 16; ++e) acc[i][j][e] = 0.f;

    const unsigned char* tb = bb + (size_t)t * 65536;
    // ---- barrier-free K-loop: coalesced global fragment loads -> MFMA ----
#pragma unroll
    for (int kt = 0; kt < 4; ++kt) {
      intx8 bf[4];
#pragma unroll
      for (int tj = 0; tj < 4; ++tj) {
        intx4 lo = *(const intx4*)(tb + tj * 8192 + kt * 2048);
        intx4 hv = *(const intx4*)(tb + tj * 8192 + kt * 2048 + 512);
        intx8 o;
#pragma unroll
        for (int w = 0; w < 4; ++w) { o[w] = lo[w]; o[4 + w] = hv[w]; }
        bf[tj] = o;
      }
#pragma unroll
      for (int ti = 0; ti < 2; ++ti)
#pragma unroll
        for (int tj = 0; tj < 4; ++tj)
          acc[ti][tj] = __builtin_amdgcn_mfma_scale_f32_32x32x64_f8f6f4(
              af[ti][kt], bf[tj], acc[ti][tj], 0, 0, 0, 127, 0, 127);
    }

    // ---- epilogue: fused argmin; ties -> smallest code; atomicMin ----
    // D layout: zrow = lane&31; code-in-tile = (reg&3) + 8*(reg>>2) + 4*hi
#pragma unroll
    for (int tj = 0; tj < 4; ++tj) {
      float best = __builtin_inff();
      int bc = 0;
#pragma unroll
      for (int ti = 0; ti < 2; ++ti)
#pragma unroll
        for (int rq = 0; rq < 4; ++rq)
#pragma unroll
          for (int rl = 0; rl < 4; ++rl) {
            float sc = fmaf(acc[ti][tj][rq * 4 + rl], -16384.f, nv[ti][rq][rl]);
            int cd = m0 + wm * 64 + ti * 32 + rq * 8 + 4 * hi + rl;
            if (sc < best) { best = sc; bc = cd; }
          }
      uint32_t u = __float_as_uint(best);
      u ^= ((uint32_t)((int32_t)u >> 31) | 0x80000000u);  // monotone-sortable
      u64 p = ((u64)u << 32) | (uint32_t)bc;
      {
        u64 o = (u64)__shfl_xor((long long)p, 32);
        p = o < p ? o : p;
      }
      if (lane < 32)
        atomicMin(&amin[cyg * 1024 + t * 256 + wn * 128 + tj * 32 + l31], p);
    }
  }
}

// ---- gather + output + per-block loss partials (8 elems/thread, amin direct) ----
__global__ __launch_bounds__(256) void gather_out(
    const float* __restrict__ z, const float* __restrict__ cb,
    const u64* __restrict__ amin,
    float* __restrict__ out, float* __restrict__ partial)
{
  const int t = threadIdx.x;
  const size_t e0 = ((size_t)blockIdx.x * 256 + t) * 8;
  const int d = (int)((e0 >> 10) & 255);
  const int b = (int)(e0 >> 18);
  const int n0 = b * 1024 + (int)(e0 & 1023);
  uint32_t kv[8];
#pragma unroll
  for (int m = 0; m < 8; ++m) kv[m] = (uint32_t)amin[n0 + m];
  floatx4 z0 = *(const floatx4*)&z[e0];
  floatx4 z1 = *(const floatx4*)&z[e0 + 4];
  floatx4 q0, q1;
#pragma unroll
  for (int m = 0; m < 4; ++m) {
    q0[m] = cb[((size_t)kv[m] << 8) + d];
    q1[m] = cb[((size_t)kv[4 + m] << 8) + d];
  }
  *(floatx4*)&out[e0] = q0;
  *(floatx4*)&out[e0 + 4] = q1;
  float s = 0.f;
#pragma unroll
  for (int m = 0; m < 4; ++m) {
    float d0 = z0[m] - q0[m], d1 = z1[m] - q1[m];
    s += d0 * d0 + d1 * d1;
  }
#pragma unroll
  for (int off = 32; off; off >>= 1) s += __shfl_down(s, off);
  __shared__ float ps[4];
  if ((t & 63) == 0) ps[t >> 6] = s;
  __syncthreads();
  if (t == 0) partial[blockIdx.x] = ps[0] + ps[1] + ps[2] + ps[3];
}

// ---- deterministic final reduction + scalar outputs ----
__global__ __launch_bounds__(256) void finalize(const float* __restrict__ partial,
                                                float* __restrict__ out)
{
  const int t = threadIdx.x;
  float s = 0.f;
#pragma unroll
  for (int i = 0; i < 16; ++i) s += partial[i * 256 + t];
#pragma unroll
  for (int off = 32; off; off >>= 1) s += __shfl_down(s, off);
  __shared__ float ps[4];
  if ((t & 63) == 0) ps[t >> 6] = s;
  __syncthreads();
  if (t == 0) {
    float m = (ps[0] + ps[1] + ps[2] + ps[3]) / (float)QELEMS;
    out[QELEMS] = m;             // codebook_loss
    out[QELEMS + 1] = 0.2f * m;  // commitment_loss
  }
}

extern "C" void kernel_launch(void* const* d_in, const int* in_sizes, int n_in,
                              void* d_out, int out_size, void* d_ws, size_t ws_size,
                              hipStream_t stream)
{
  const float* z = (const float*)d_in[0];
  const float* cb = (const float*)d_in[1];
  float* out = (float*)d_out;
  char* ws = (char*)d_ws;

  // ws layout (bytes)
  unsigned char* z8f = (unsigned char*)(ws + 0);        //  8,388,608
  unsigned char* c8f = (unsigned char*)(ws + 8388608);  //  2,097,152
  float* norms = (float*)(ws + 10485760);               //    131,072 (padded)
  u64* amin = (u64*)(ws + 10616832);                    //    262,144
  float* lpart = (float*)(ws + 10878976);               //     16,384
  // total: 10,895,360 bytes

  prep_all<<<3088, 256, 0, stream>>>(z, cb, z8f, c8f, norms, amin);
  gemm_argmin<<<2048, 256, 0, stream>>>(z8f, c8f, norms, amin);
  gather_out<<<QELEMS / 2048, 256, 0, stream>>>(z, cb, amin, out, lpart);
  finalize<<<1, 256, 0, stream>>>(lpart, out);
}